// Round 1
// baseline (1337.803 us; speedup 1.0000x reference)
//
#include <hip/hip_runtime.h>

typedef unsigned short u16;
typedef unsigned int u32;
typedef __attribute__((ext_vector_type(8))) __bf16 bf16x8;
typedef __attribute__((ext_vector_type(4))) float f32x4;

// ---------- helpers ----------
__device__ __forceinline__ u16 f2bf(float f) {
  union { float f; u32 u; } v; v.f = f;
  u32 r = v.u + 0x7fffu + ((v.u >> 16) & 1u);   // RNE
  return (u16)(r >> 16);
}
__device__ __forceinline__ float bf2f(u16 h) {
  return __uint_as_float(((u32)h) << 16);
}
// async global->LDS, 16B per lane. LDS dest = wave-uniform base + lane*16.
__device__ __forceinline__ void gld16(void* lds, const void* g) {
  __builtin_amdgcn_global_load_lds(
      (__attribute__((address_space(1))) void*)g,
      (__attribute__((address_space(3))) void*)lds, 16, 0, 0);
}

// ---------- X conversion: fp32 -> bf16, 8 elems/thread ----------
__global__ void convert_x(const float* __restrict__ src, u16* __restrict__ dst) {
  const size_t c = (size_t)blockIdx.x * blockDim.x + threadIdx.x;  // chunk of 8
  const float* s = src + c * 8;
  u16 t[8];
#pragma unroll
  for (int i = 0; i < 8; ++i) t[i] = f2bf(s[i]);
  ((uint4*)dst)[c] = *(const uint4*)t;
}

// ---------- weight transpose: src (K x N, fp32) -> dst (N x K, bf16) ----------
__global__ void transpose_w(const float* __restrict__ srcf, u16* __restrict__ dst,
                            int K, int N) {
  __shared__ u16 tile[64][72];
  const int r0 = blockIdx.y * 64, c0 = blockIdx.x * 64;
  const int tr = threadIdx.x >> 2;          // 0..63
  const int tc = (threadIdx.x & 3) * 16;    // 0,16,32,48
  const float* src = srcf + (size_t)(r0 + tr) * N + c0 + tc;
  u16* t = &tile[tr][tc];
#pragma unroll
  for (int i = 0; i < 16; ++i) t[i] = f2bf(src[i]);
  __syncthreads();
  u16 tmp[16];
#pragma unroll
  for (int i = 0; i < 16; ++i) tmp[i] = tile[tc + i][tr];
  uint4* gd = (uint4*)(dst + (size_t)(c0 + tr) * K + r0 + tc);
  gd[0] = *(uint4*)&tmp[0];
  gd[1] = *(uint4*)&tmp[8];
}

// ---------- V transpose: V (b*2048+s, h*128+d) -> Vt[((b*8+h)*128+d)*2048 + s] ----------
__global__ void transpose_v(const u16* __restrict__ V, u16* __restrict__ Vt) {
  __shared__ u16 tile[64][72];
  const int z = blockIdx.z, b = z >> 3, h = z & 7;
  const int s0 = blockIdx.y * 64;   // s tile
  const int d0 = blockIdx.x * 64;   // d tile
  const u16* src = V + ((size_t)(b * 2048 + s0)) * 1024 + h * 128 + d0;
  u16* dst = Vt + ((size_t)((b * 8 + h) * 128 + d0)) * 2048 + s0;
  const int tr = threadIdx.x >> 2;
  const int tc = (threadIdx.x & 3) * 16;
  const uint4* gs = (const uint4*)(src + (size_t)tr * 1024 + tc);
  *(uint4*)&tile[tr][tc] = gs[0];
  *(uint4*)&tile[tr][tc + 8] = gs[1];
  __syncthreads();
  u16 tmp[16];
#pragma unroll
  for (int i = 0; i < 16; ++i) tmp[i] = tile[tc + i][tr];
  uint4* gd = (uint4*)(dst + (size_t)tr * 2048 + tc);
  gd[0] = *(uint4*)&tmp[0];
  gd[1] = *(uint4*)&tmp[8];
}

// ---------- GEMM: C[M,N] = A[M,K] * B[K,N], B given transposed (N x K) ----------
// bf16 in, fp32 acc, output bf16 (OUT32=0) or fp32 (OUT32=1).
// Tile 128x128, BK=64, 256 threads, wave -> 64x64.
// m97 structure: global_load_lds width-16 staging into linear LDS (no reg round-trip).
template <int OUT32>
__global__ __launch_bounds__(256, 2) void gemm_bt128(
    const u16* __restrict__ A, const u16* __restrict__ Bt,
    void* __restrict__ Cv, int K, int N) {
  __shared__ u16 As[128 * 64];
  __shared__ u16 Bs[128 * 64];
  const int tid = threadIdx.x;
  const int wave = tid >> 6, lane = tid & 63;
  const int m0 = blockIdx.y * 128, n0 = blockIdx.x * 128;
  const int wr = (wave >> 1) * 64, wc = (wave & 1) * 64;
  const int lrow = lane & 15, quad = lane >> 4;
  const int cbase = wave * 64 + lane;     // chunk id (16B chunks), r=0

  f32x4 acc[4][4];
#pragma unroll
  for (int i = 0; i < 4; ++i)
#pragma unroll
    for (int j = 0; j < 4; ++j) acc[i][j] = (f32x4){0.f, 0.f, 0.f, 0.f};

  for (int k0 = 0; k0 < K; k0 += 64) {
    // stage A+B tiles: 1024 chunks each; wave fills 64 consecutive chunks/iter
#pragma unroll
    for (int r = 0; r < 4; ++r) {
      const int c = r * 256 + cbase;          // 0..1023
      const int row = c >> 3, col = (c & 7) * 8;
      gld16(&As[(size_t)(r * 4 + wave) * 512],
            A + (size_t)(m0 + row) * K + k0 + col);
      gld16(&Bs[(size_t)(r * 4 + wave) * 512],
            Bt + (size_t)(n0 + row) * K + k0 + col);
    }
    __syncthreads();   // drains vmcnt(0): tiles resident
#pragma unroll
    for (int kk = 0; kk < 2; ++kk) {
      const int ko = kk * 32 + quad * 8;
      bf16x8 af[4], bfr[4];
#pragma unroll
      for (int i = 0; i < 4; ++i)
        af[i] = *(const bf16x8*)&As[(wr + i * 16 + lrow) * 64 + ko];
#pragma unroll
      for (int j = 0; j < 4; ++j)
        bfr[j] = *(const bf16x8*)&Bs[(wc + j * 16 + lrow) * 64 + ko];
#pragma unroll
      for (int i = 0; i < 4; ++i)
#pragma unroll
        for (int j = 0; j < 4; ++j)
          acc[i][j] = __builtin_amdgcn_mfma_f32_16x16x32_bf16(af[i], bfr[j], acc[i][j], 0, 0, 0);
    }
    __syncthreads();
  }
  // epilogue: C/D layout col=lane&15, row=quad*4+reg
#pragma unroll
  for (int i = 0; i < 4; ++i)
#pragma unroll
    for (int j = 0; j < 4; ++j)
#pragma unroll
      for (int reg = 0; reg < 4; ++reg) {
        const int row = m0 + wr + i * 16 + quad * 4 + reg;
        const int col = n0 + wc + j * 16 + lrow;
        if (OUT32)
          ((float*)Cv)[(size_t)row * N + col] = acc[i][j][reg];
        else
          ((u16*)Cv)[(size_t)row * N + col] = f2bf(acc[i][j][reg]);
      }
}

// ---------- RoPE in-place on Q (4096x4096) and K (4096x1024) ----------
__global__ void rope_kernel(u16* __restrict__ Q, u16* __restrict__ Kc) {
  const int row = blockIdx.x;               // b*2048 + s
  const float p = (float)(row & 2047);
  for (int t = threadIdx.x; t < 2560; t += 256) {
    u16* base;
    int d;
    if (t < 2048) { const int h = t >> 6; d = t & 63; base = Q + (size_t)row * 4096 + h * 128; }
    else { const int tt = t - 2048; const int h = tt >> 6; d = tt & 63; base = Kc + (size_t)row * 1024 + h * 128; }
    const float inv = exp2f((float)d * -0.20762050593046807f);  // 10000^(-d/64)
    const float f = p * inv;
    float s, c;
    sincosf(f, &s, &c);
    const float x1 = bf2f(base[d]);
    const float x2 = bf2f(base[d + 64]);
    base[d] = f2bf(x1 * c - x2 * s);
    base[d + 64] = f2bf(x2 * c + x1 * s);
  }
}

// ---------- flash attention ----------
// grid (qtile=16, qhead=32, b=2), 256 threads. Wave owns 32 q-rows.
// KV-tile = 64. Static LDS 51200 B. Q frags in registers.
// Pipelined staging: V(cur) issued at loop top (drains at mid barrier, hidden
// under QK^T+softmax); K(next) issued after mid barrier (drains at loop-end
// barrier, hidden under PV). All buffer overwrites are barrier-separated from
// their readers; __syncthreads drains vmcnt(0) for the cooperative staging.
__global__ __launch_bounds__(256, 1) void attn(
    const u16* __restrict__ Q, const u16* __restrict__ Kc,
    const u16* __restrict__ Vt, u16* __restrict__ O) {
  __shared__ u16 smem[25600];   // 51200 bytes
  u16* Qs = smem;               // overlay: 128x128 (16384) for initial Q staging
  u16* Ks = smem;               // 64 x 128 (8192)
  u16* Vs = smem + 8192;        // 128 x 64 (8192)  row=d, col=key
  u16* Ps = smem + 16384;       // 128 x 72 (9216)  padded
  const int tid = threadIdx.x, wave = tid >> 6, lane = tid & 63;
  const int qt = blockIdx.x, qh = blockIdx.y, b = blockIdx.z;
  const int kvh = qh >> 2;
  const int lrow = lane & 15, quad = lane >> 4;
  const float cs = 0.088388347762774597f * 1.4426950408889634f;  // scale*log2(e)

  // ---- stage Q tile (128 x 128) via global_load_lds, pull frags to registers ----
  const u16* qb = Q + ((size_t)(b * 2048 + qt * 128)) * 4096 + qh * 128;
#pragma unroll
  for (int r = 0; r < 8; ++r) {
    const int c = (r * 4 + wave) * 64 + lane;   // 0..2047 chunks
    gld16(&Qs[(size_t)(r * 4 + wave) * 512],
          qb + (size_t)(c >> 4) * 4096 + (c & 15) * 8);
  }
  __syncthreads();
  bf16x8 aq[2][4];
#pragma unroll
  for (int i = 0; i < 2; ++i)
#pragma unroll
    for (int kk = 0; kk < 4; ++kk)
      aq[i][kk] = *(const bf16x8*)&Qs[(wave * 32 + i * 16 + lrow) * 128 + kk * 32 + quad * 8];
  __syncthreads();

  // ---- prologue: stage K(0), then drain so first QK^T sees it ----
  {
    const u16* kb = Kc + ((size_t)(b * 2048)) * 1024 + kvh * 128;
#pragma unroll
    for (int r = 0; r < 4; ++r) {
      const int c = (r * 4 + wave) * 64 + lane;   // 0..1023 chunks
      gld16(&Ks[(size_t)(r * 4 + wave) * 512],
            kb + (size_t)(c >> 4) * 1024 + (c & 15) * 8);
    }
  }
  __syncthreads();

  f32x4 acco[2][8];
#pragma unroll
  for (int i = 0; i < 2; ++i)
#pragma unroll
    for (int j = 0; j < 8; ++j) acco[i][j] = (f32x4){0.f, 0.f, 0.f, 0.f};
  float m_i[8], l_i[8];
#pragma unroll
  for (int i = 0; i < 8; ++i) { m_i[i] = -INFINITY; l_i[i] = 0.f; }

  const u16* vbase = Vt + ((size_t)((b * 8 + kvh) * 128)) * 2048;

  for (int kv0 = 0; kv0 < 2048; kv0 += 64) {
    // ---- issue V(kv0): 128 d x 64 keys; hides under QK^T + softmax ----
#pragma unroll
    for (int r = 0; r < 4; ++r) {
      const int c = (r * 4 + wave) * 64 + lane;   // 0..1023 chunks
      gld16(&Vs[(size_t)(r * 4 + wave) * 512],
            vbase + (size_t)(c >> 3) * 2048 + kv0 + (c & 7) * 8);
    }

    // ---- S = Q K^T for this wave's 32 rows x 64 keys ----
    f32x4 s[2][4];
#pragma unroll
    for (int i = 0; i < 2; ++i)
#pragma unroll
      for (int j = 0; j < 4; ++j) s[i][j] = (f32x4){0.f, 0.f, 0.f, 0.f};
    __builtin_amdgcn_s_setprio(1);
#pragma unroll
    for (int kk = 0; kk < 4; ++kk) {
      const int ko = kk * 32 + quad * 8;
#pragma unroll
      for (int j = 0; j < 4; ++j) {
        const bf16x8 bk = *(const bf16x8*)&Ks[(j * 16 + lrow) * 128 + ko];
        s[0][j] = __builtin_amdgcn_mfma_f32_16x16x32_bf16(aq[0][kk], bk, s[0][j], 0, 0, 0);
        s[1][j] = __builtin_amdgcn_mfma_f32_16x16x32_bf16(aq[1][kk], bk, s[1][j], 0, 0, 0);
      }
    }
    __builtin_amdgcn_s_setprio(0);

    // ---- online softmax (raw-domain max; exp via exp2 in scaled domain) ----
#pragma unroll
    for (int i = 0; i < 2; ++i) {
#pragma unroll
      for (int reg = 0; reg < 4; ++reg) {
        float mx = s[i][0][reg];
#pragma unroll
        for (int j = 1; j < 4; ++j) mx = fmaxf(mx, s[i][j][reg]);
        mx = fmaxf(mx, __shfl_xor(mx, 1));
        mx = fmaxf(mx, __shfl_xor(mx, 2));
        mx = fmaxf(mx, __shfl_xor(mx, 4));
        mx = fmaxf(mx, __shfl_xor(mx, 8));
        const int idx = i * 4 + reg;
        const float mnew = fmaxf(m_i[idx], mx);
        const float al = exp2f((m_i[idx] - mnew) * cs);
        m_i[idx] = mnew;
        float rsum = 0.f;
#pragma unroll
        for (int j = 0; j < 4; ++j) {
          const float p0 = exp2f((s[i][j][reg] - mnew) * cs);
          s[i][j][reg] = p0;
          rsum += p0;
        }
        rsum += __shfl_xor(rsum, 1);
        rsum += __shfl_xor(rsum, 2);
        rsum += __shfl_xor(rsum, 4);
        rsum += __shfl_xor(rsum, 8);
        l_i[idx] = l_i[idx] * al + rsum;
#pragma unroll
        for (int j = 0; j < 8; ++j) acco[i][j][reg] *= al;
      }
    }

    // ---- P -> LDS (bf16), padded stride 72 ----
#pragma unroll
    for (int i = 0; i < 2; ++i)
#pragma unroll
      for (int j = 0; j < 4; ++j)
#pragma unroll
        for (int reg = 0; reg < 4; ++reg)
          Ps[(wave * 32 + i * 16 + quad * 4 + reg) * 72 + j * 16 + lrow] = f2bf(s[i][j][reg]);
    __syncthreads();   // drains V loads + P writes; all waves past QK^T (Ks free)

    // ---- issue K(kv0+64): hides under PV ----
    if (kv0 + 64 < 2048) {
      const u16* kb = Kc + ((size_t)(b * 2048 + kv0 + 64)) * 1024 + kvh * 128;
#pragma unroll
      for (int r = 0; r < 4; ++r) {
        const int c = (r * 4 + wave) * 64 + lane;
        gld16(&Ks[(size_t)(r * 4 + wave) * 512],
              kb + (size_t)(c >> 4) * 1024 + (c & 15) * 8);
      }
    }

    // ---- O += P V  (A-frags from Ps, B-frags from Vs: Vs[d][key] == V[key][d]) ----
    __builtin_amdgcn_s_setprio(1);
#pragma unroll
    for (int kk = 0; kk < 2; ++kk) {
      const int ko = kk * 32 + quad * 8;
      bf16x8 ap[2];
      ap[0] = *(const bf16x8*)&Ps[(wave * 32 + lrow) * 72 + ko];
      ap[1] = *(const bf16x8*)&Ps[(wave * 32 + 16 + lrow) * 72 + ko];
#pragma unroll
      for (int j = 0; j < 8; ++j) {
        const bf16x8 bv = *(const bf16x8*)&Vs[(j * 16 + lrow) * 64 + ko];
        acco[0][j] = __builtin_amdgcn_mfma_f32_16x16x32_bf16(ap[0], bv, acco[0][j], 0, 0, 0);
        acco[1][j] = __builtin_amdgcn_mfma_f32_16x16x32_bf16(ap[1], bv, acco[1][j], 0, 0, 0);
      }
    }
    __builtin_amdgcn_s_setprio(0);
    __syncthreads();   // drains K(next) prefetch; PV reads of Vs/Ps complete
  }

  // ---- epilogue: O[b*2048+q, qh*128+d] = acco / l ----
#pragma unroll
  for (int i = 0; i < 2; ++i)
#pragma unroll
    for (int reg = 0; reg < 4; ++reg) {
      const float inv = 1.0f / l_i[i * 4 + reg];
      const int row = b * 2048 + qt * 128 + wave * 32 + i * 16 + quad * 4 + reg;
#pragma unroll
      for (int j = 0; j < 8; ++j) {
        const int col = qh * 128 + j * 16 + lrow;
        O[(size_t)row * 4096 + col] = f2bf(acco[i][j][reg] * inv);
      }
    }
}

// ---------- launch ----------
extern "C" void kernel_launch(void* const* d_in, const int* in_sizes, int n_in,
                              void* d_out, int out_size, void* d_ws, size_t ws_size,
                              hipStream_t stream) {
  const float* X  = (const float*)d_in[0];
  const float* Wq = (const float*)d_in[2];
  const float* Wk = (const float*)d_in[3];
  const float* Wv = (const float*)d_in[4];
  const float* Wo = (const float*)d_in[5];
  u16* ws = (u16*)d_ws;

  // workspace (u16 elements), ~120 MiB total:
  // Xb(16.7M) | R0(16.7M) | R1(16.7M) | R2(4.2M) | R3(4.2M) | R4(4.2M)
  u16* Xb = ws;
  u16* R0 = Xb + 16777216;
  u16* R1 = R0 + 16777216;
  u16* R2 = R1 + 16777216;
  u16* R3 = R2 + 4194304;
  u16* R4 = R3 + 4194304;
  u16* Qb = R1, *Kb = R3, *Vb = R4, *Vt = R2, *Ob = R0, *WoT = R1;

  convert_x<<<8192, 256, 0, stream>>>(X, Xb);

  transpose_w<<<dim3(64, 64), 256, 0, stream>>>(Wq, R0, 4096, 4096);
  gemm_bt128<0><<<dim3(32, 32), 256, 0, stream>>>(Xb, R0, Qb, 4096, 4096);

  transpose_w<<<dim3(16, 64), 256, 0, stream>>>(Wk, R0, 4096, 1024);
  gemm_bt128<0><<<dim3(8, 32), 256, 0, stream>>>(Xb, R0, Kb, 4096, 1024);

  transpose_w<<<dim3(16, 64), 256, 0, stream>>>(Wv, R0, 4096, 1024);
  gemm_bt128<0><<<dim3(8, 32), 256, 0, stream>>>(Xb, R0, Vb, 4096, 1024);

  rope_kernel<<<4096, 256, 0, stream>>>(Qb, Kb);
  transpose_v<<<dim3(2, 32, 16), 256, 0, stream>>>(Vb, Vt);

  attn<<<dim3(16, 32, 2), 256, 0, stream>>>(Qb, Kb, Vt, Ob);

  transpose_w<<<dim3(64, 64), 256, 0, stream>>>(Wo, WoT, 4096, 4096);
  gemm_bt128<1><<<dim3(32, 32), 256, 0, stream>>>(Ob, WoT, d_out, 4096, 4096);
}

// Round 2
// 1256.813 us; speedup vs baseline: 1.0644x; 1.0644x over previous
//
#include <hip/hip_runtime.h>

typedef unsigned short u16;
typedef unsigned int u32;
typedef __attribute__((ext_vector_type(8))) __bf16 bf16x8;
typedef __attribute__((ext_vector_type(4))) float f32x4;

// ---------- helpers ----------
__device__ __forceinline__ u16 f2bf(float f) {
  union { float f; u32 u; } v; v.f = f;
  u32 r = v.u + 0x7fffu + ((v.u >> 16) & 1u);   // RNE
  return (u16)(r >> 16);
}
__device__ __forceinline__ float bf2f(u16 h) {
  return __uint_as_float(((u32)h) << 16);
}
// async global->LDS, 16B per lane. LDS dest = wave-uniform base + lane*16.
__device__ __forceinline__ void gld16(void* lds, const void* g) {
  __builtin_amdgcn_global_load_lds(
      (__attribute__((address_space(1))) void*)g,
      (__attribute__((address_space(3))) void*)lds, 16, 0, 0);
}

// ---------- X conversion: fp32 -> bf16, 8 elems/thread ----------
__global__ void convert_x(const float* __restrict__ src, u16* __restrict__ dst) {
  const size_t c = (size_t)blockIdx.x * blockDim.x + threadIdx.x;  // chunk of 8
  const float* s = src + c * 8;
  u16 t[8];
#pragma unroll
  for (int i = 0; i < 8; ++i) t[i] = f2bf(s[i]);
  ((uint4*)dst)[c] = *(const uint4*)t;
}

// ---------- weight transpose: src (K x N, fp32) -> dst (N x K, bf16) ----------
__global__ void transpose_w(const float* __restrict__ srcf, u16* __restrict__ dst,
                            int K, int N) {
  __shared__ u16 tile[64][72];
  const int r0 = blockIdx.y * 64, c0 = blockIdx.x * 64;
  const int tr = threadIdx.x >> 2;          // 0..63
  const int tc = (threadIdx.x & 3) * 16;    // 0,16,32,48
  const float* src = srcf + (size_t)(r0 + tr) * N + c0 + tc;
  u16* t = &tile[tr][tc];
#pragma unroll
  for (int i = 0; i < 16; ++i) t[i] = f2bf(src[i]);
  __syncthreads();
  u16 tmp[16];
#pragma unroll
  for (int i = 0; i < 16; ++i) tmp[i] = tile[tc + i][tr];
  uint4* gd = (uint4*)(dst + (size_t)(c0 + tr) * K + r0 + tc);
  gd[0] = *(uint4*)&tmp[0];
  gd[1] = *(uint4*)&tmp[8];
}

// ---------- V transpose: V (b*2048+s, h*128+d) -> Vt[((b*8+h)*128+d)*2048 + s] ----------
__global__ void transpose_v(const u16* __restrict__ V, u16* __restrict__ Vt) {
  __shared__ u16 tile[64][72];
  const int z = blockIdx.z, b = z >> 3, h = z & 7;
  const int s0 = blockIdx.y * 64;   // s tile
  const int d0 = blockIdx.x * 64;   // d tile
  const u16* src = V + ((size_t)(b * 2048 + s0)) * 1024 + h * 128 + d0;
  u16* dst = Vt + ((size_t)((b * 8 + h) * 128 + d0)) * 2048 + s0;
  const int tr = threadIdx.x >> 2;
  const int tc = (threadIdx.x & 3) * 16;
  const uint4* gs = (const uint4*)(src + (size_t)tr * 1024 + tc);
  *(uint4*)&tile[tr][tc] = gs[0];
  *(uint4*)&tile[tr][tc + 8] = gs[1];
  __syncthreads();
  u16 tmp[16];
#pragma unroll
  for (int i = 0; i < 16; ++i) tmp[i] = tile[tc + i][tr];
  uint4* gd = (uint4*)(dst + (size_t)tr * 2048 + tc);
  gd[0] = *(uint4*)&tmp[0];
  gd[1] = *(uint4*)&tmp[8];
}

// ---------- GEMM: C[M,N] = A[M,K] * B[K,N], B given transposed (N x K) ----------
// bf16 in, fp32 acc, output bf16 (OUT32=0) or fp32 (OUT32=1).
// Tile 128x128, BK=64, 256 threads, wave -> 64x64.
// m97 structure: global_load_lds width-16 staging into linear LDS.
// (No LDS swizzle here: T2 is measured-null on 128^2 2-phase structures.)
template <int OUT32>
__global__ __launch_bounds__(256, 2) void gemm_bt128(
    const u16* __restrict__ A, const u16* __restrict__ Bt,
    void* __restrict__ Cv, int K, int N) {
  __shared__ u16 As[128 * 64];
  __shared__ u16 Bs[128 * 64];
  const int tid = threadIdx.x;
  const int wave = tid >> 6, lane = tid & 63;
  const int m0 = blockIdx.y * 128, n0 = blockIdx.x * 128;
  const int wr = (wave >> 1) * 64, wc = (wave & 1) * 64;
  const int lrow = lane & 15, quad = lane >> 4;
  const int cbase = wave * 64 + lane;     // chunk id (16B chunks), r=0

  f32x4 acc[4][4];
#pragma unroll
  for (int i = 0; i < 4; ++i)
#pragma unroll
    for (int j = 0; j < 4; ++j) acc[i][j] = (f32x4){0.f, 0.f, 0.f, 0.f};

  for (int k0 = 0; k0 < K; k0 += 64) {
    // stage A+B tiles: 1024 chunks each; wave fills 64 consecutive chunks/iter
#pragma unroll
    for (int r = 0; r < 4; ++r) {
      const int c = r * 256 + cbase;          // 0..1023
      const int row = c >> 3, col = (c & 7) * 8;
      gld16(&As[(size_t)(r * 4 + wave) * 512],
            A + (size_t)(m0 + row) * K + k0 + col);
      gld16(&Bs[(size_t)(r * 4 + wave) * 512],
            Bt + (size_t)(n0 + row) * K + k0 + col);
    }
    __syncthreads();   // drains vmcnt(0): tiles resident
#pragma unroll
    for (int kk = 0; kk < 2; ++kk) {
      const int ko = kk * 32 + quad * 8;
      bf16x8 af[4], bfr[4];
#pragma unroll
      for (int i = 0; i < 4; ++i)
        af[i] = *(const bf16x8*)&As[(wr + i * 16 + lrow) * 64 + ko];
#pragma unroll
      for (int j = 0; j < 4; ++j)
        bfr[j] = *(const bf16x8*)&Bs[(wc + j * 16 + lrow) * 64 + ko];
#pragma unroll
      for (int i = 0; i < 4; ++i)
#pragma unroll
        for (int j = 0; j < 4; ++j)
          acc[i][j] = __builtin_amdgcn_mfma_f32_16x16x32_bf16(af[i], bfr[j], acc[i][j], 0, 0, 0);
    }
    __syncthreads();
  }
  // epilogue: C/D layout col=lane&15, row=quad*4+reg
#pragma unroll
  for (int i = 0; i < 4; ++i)
#pragma unroll
    for (int j = 0; j < 4; ++j)
#pragma unroll
      for (int reg = 0; reg < 4; ++reg) {
        const int row = m0 + wr + i * 16 + quad * 4 + reg;
        const int col = n0 + wc + j * 16 + lrow;
        if (OUT32)
          ((float*)Cv)[(size_t)row * N + col] = acc[i][j][reg];
        else
          ((u16*)Cv)[(size_t)row * N + col] = f2bf(acc[i][j][reg]);
      }
}

// ---------- RoPE in-place on Q (4096x4096) and K (4096x1024) ----------
__global__ void rope_kernel(u16* __restrict__ Q, u16* __restrict__ Kc) {
  const int row = blockIdx.x;               // b*2048 + s
  const float p = (float)(row & 2047);
  for (int t = threadIdx.x; t < 2560; t += 256) {
    u16* base;
    int d;
    if (t < 2048) { const int h = t >> 6; d = t & 63; base = Q + (size_t)row * 4096 + h * 128; }
    else { const int tt = t - 2048; const int h = tt >> 6; d = tt & 63; base = Kc + (size_t)row * 1024 + h * 128; }
    const float inv = exp2f((float)d * -0.20762050593046807f);  // 10000^(-d/64)
    const float f = p * inv;
    float s, c;
    sincosf(f, &s, &c);
    const float x1 = bf2f(base[d]);
    const float x2 = bf2f(base[d + 64]);
    base[d] = f2bf(x1 * c - x2 * s);
    base[d + 64] = f2bf(x2 * c + x1 * s);
  }
}

// ---------- flash attention ----------
// grid (qtile=16, qhead=32, b=2), 256 threads. Wave owns 32 q-rows.
// KV-tile = 64. Static LDS 51200 B. Q frags in registers.
//
// LDS XOR-swizzle (rule #21 both-sides pattern): global_load_lds writes
// linearly, so the SOURCE chunk column is pre-permuted (scol = col ^ (row&7),
// 16B-chunk units) and every LDS read XORs the same mask into its address
// (element offset ^= (row&7)<<3  ==  byte ^= (row&7)<<4). Involution => data
// bit-exact; kills the 16-way bank conflicts on the stride-256B (Ks/Qs) and
// stride-128B (Vs) row-major tiles.
//
// Pipelined staging: V(cur) issued at loop top (drains at mid barrier, hidden
// under QK^T+softmax); K(next) issued after mid barrier (drains at loop-end
// barrier, hidden under PV).
__global__ __launch_bounds__(256, 1) void attn(
    const u16* __restrict__ Q, const u16* __restrict__ Kc,
    const u16* __restrict__ Vt, u16* __restrict__ O) {
  __shared__ u16 smem[25600];   // 51200 bytes
  u16* Qs = smem;               // overlay: 128x128 (16384) for initial Q staging
  u16* Ks = smem;               // 64 x 128 (8192)
  u16* Vs = smem + 8192;        // 128 x 64 (8192)  row=d, col=key
  u16* Ps = smem + 16384;       // 128 x 72 (9216)  padded
  const int tid = threadIdx.x, wave = tid >> 6, lane = tid & 63;
  const int qt = blockIdx.x, qh = blockIdx.y, b = blockIdx.z;
  const int kvh = qh >> 2;
  const int lrow = lane & 15, quad = lane >> 4;
  const int swz = (lrow & 7) << 3;          // read-side XOR, element units
  const float cs = 0.088388347762774597f * 1.4426950408889634f;  // scale*log2(e)

  // ---- stage Q tile (128 x 128) via global_load_lds (swizzled source) ----
  const u16* qb = Q + ((size_t)(b * 2048 + qt * 128)) * 4096 + qh * 128;
#pragma unroll
  for (int r = 0; r < 8; ++r) {
    const int c = (r * 4 + wave) * 64 + lane;   // 0..2047 chunks
    const int row = c >> 4, scol = (c & 15) ^ (row & 7);
    gld16(&Qs[(size_t)(r * 4 + wave) * 512],
          qb + (size_t)row * 4096 + scol * 8);
  }
  __syncthreads();
  bf16x8 aq[2][4];
#pragma unroll
  for (int i = 0; i < 2; ++i)
#pragma unroll
    for (int kk = 0; kk < 4; ++kk)
      aq[i][kk] = *(const bf16x8*)
          &Qs[(wave * 32 + i * 16 + lrow) * 128 + ((kk * 32 + quad * 8) ^ swz)];
  __syncthreads();

  // ---- prologue: stage K(0) (swizzled source), drain before first QK^T ----
  {
    const u16* kb = Kc + ((size_t)(b * 2048)) * 1024 + kvh * 128;
#pragma unroll
    for (int r = 0; r < 4; ++r) {
      const int c = (r * 4 + wave) * 64 + lane;   // 0..1023 chunks
      const int row = c >> 4, scol = (c & 15) ^ (row & 7);
      gld16(&Ks[(size_t)(r * 4 + wave) * 512],
            kb + (size_t)row * 1024 + scol * 8);
    }
  }
  __syncthreads();

  f32x4 acco[2][8];
#pragma unroll
  for (int i = 0; i < 2; ++i)
#pragma unroll
    for (int j = 0; j < 8; ++j) acco[i][j] = (f32x4){0.f, 0.f, 0.f, 0.f};
  float m_i[8], l_i[8];
#pragma unroll
  for (int i = 0; i < 8; ++i) { m_i[i] = -INFINITY; l_i[i] = 0.f; }

  const u16* vbase = Vt + ((size_t)((b * 8 + kvh) * 128)) * 2048;

  for (int kv0 = 0; kv0 < 2048; kv0 += 64) {
    // ---- issue V(kv0): 128 d x 64 keys (swizzled source); hides under QK^T ----
#pragma unroll
    for (int r = 0; r < 4; ++r) {
      const int c = (r * 4 + wave) * 64 + lane;   // 0..1023 chunks
      const int row = c >> 3, scol = (c & 7) ^ (row & 7);
      gld16(&Vs[(size_t)(r * 4 + wave) * 512],
            vbase + (size_t)row * 2048 + kv0 + scol * 8);
    }

    // ---- S = Q K^T for this wave's 32 rows x 64 keys ----
    f32x4 s[2][4];
#pragma unroll
    for (int i = 0; i < 2; ++i)
#pragma unroll
      for (int j = 0; j < 4; ++j) s[i][j] = (f32x4){0.f, 0.f, 0.f, 0.f};
    __builtin_amdgcn_s_setprio(1);
#pragma unroll
    for (int kk = 0; kk < 4; ++kk) {
      const int ko = (kk * 32 + quad * 8) ^ swz;
#pragma unroll
      for (int j = 0; j < 4; ++j) {
        const bf16x8 bk = *(const bf16x8*)&Ks[(j * 16 + lrow) * 128 + ko];
        s[0][j] = __builtin_amdgcn_mfma_f32_16x16x32_bf16(aq[0][kk], bk, s[0][j], 0, 0, 0);
        s[1][j] = __builtin_amdgcn_mfma_f32_16x16x32_bf16(aq[1][kk], bk, s[1][j], 0, 0, 0);
      }
    }
    __builtin_amdgcn_s_setprio(0);

    // ---- online softmax (raw-domain max; exp via exp2 in scaled domain) ----
#pragma unroll
    for (int i = 0; i < 2; ++i) {
#pragma unroll
      for (int reg = 0; reg < 4; ++reg) {
        float mx = s[i][0][reg];
#pragma unroll
        for (int j = 1; j < 4; ++j) mx = fmaxf(mx, s[i][j][reg]);
        mx = fmaxf(mx, __shfl_xor(mx, 1));
        mx = fmaxf(mx, __shfl_xor(mx, 2));
        mx = fmaxf(mx, __shfl_xor(mx, 4));
        mx = fmaxf(mx, __shfl_xor(mx, 8));
        const int idx = i * 4 + reg;
        const float mnew = fmaxf(m_i[idx], mx);
        const float al = exp2f((m_i[idx] - mnew) * cs);
        m_i[idx] = mnew;
        float rsum = 0.f;
#pragma unroll
        for (int j = 0; j < 4; ++j) {
          const float p0 = exp2f((s[i][j][reg] - mnew) * cs);
          s[i][j][reg] = p0;
          rsum += p0;
        }
        rsum += __shfl_xor(rsum, 1);
        rsum += __shfl_xor(rsum, 2);
        rsum += __shfl_xor(rsum, 4);
        rsum += __shfl_xor(rsum, 8);
        l_i[idx] = l_i[idx] * al + rsum;
#pragma unroll
        for (int j = 0; j < 8; ++j) acco[i][j][reg] *= al;
      }
    }

    // ---- P -> LDS (bf16), padded stride 72 ----
#pragma unroll
    for (int i = 0; i < 2; ++i)
#pragma unroll
      for (int j = 0; j < 4; ++j)
#pragma unroll
        for (int reg = 0; reg < 4; ++reg)
          Ps[(wave * 32 + i * 16 + quad * 4 + reg) * 72 + j * 16 + lrow] = f2bf(s[i][j][reg]);
    __syncthreads();   // drains V loads + P writes; all waves past QK^T (Ks free)

    // ---- issue K(kv0+64) (swizzled source): hides under PV ----
    if (kv0 + 64 < 2048) {
      const u16* kb = Kc + ((size_t)(b * 2048 + kv0 + 64)) * 1024 + kvh * 128;
#pragma unroll
      for (int r = 0; r < 4; ++r) {
        const int c = (r * 4 + wave) * 64 + lane;
        const int row = c >> 4, scol = (c & 15) ^ (row & 7);
        gld16(&Ks[(size_t)(r * 4 + wave) * 512],
              kb + (size_t)row * 1024 + scol * 8);
      }
    }

    // ---- O += P V  (A-frags from Ps, B-frags from swizzled Vs) ----
    __builtin_amdgcn_s_setprio(1);
#pragma unroll
    for (int kk = 0; kk < 2; ++kk) {
      const int ko = kk * 32 + quad * 8;
      bf16x8 ap[2];
      ap[0] = *(const bf16x8*)&Ps[(wave * 32 + lrow) * 72 + ko];
      ap[1] = *(const bf16x8*)&Ps[(wave * 32 + 16 + lrow) * 72 + ko];
      const int kov = ko ^ swz;
#pragma unroll
      for (int j = 0; j < 8; ++j) {
        const bf16x8 bv = *(const bf16x8*)&Vs[(j * 16 + lrow) * 64 + kov];
        acco[0][j] = __builtin_amdgcn_mfma_f32_16x16x32_bf16(ap[0], bv, acco[0][j], 0, 0, 0);
        acco[1][j] = __builtin_amdgcn_mfma_f32_16x16x32_bf16(ap[1], bv, acco[1][j], 0, 0, 0);
      }
    }
    __builtin_amdgcn_s_setprio(0);
    __syncthreads();   // drains K(next) prefetch; PV reads of Vs/Ps complete
  }

  // ---- epilogue: O[b*2048+q, qh*128+d] = acco / l ----
#pragma unroll
  for (int i = 0; i < 2; ++i)
#pragma unroll
    for (int reg = 0; reg < 4; ++reg) {
      const float inv = 1.0f / l_i[i * 4 + reg];
      const int row = b * 2048 + qt * 128 + wave * 32 + i * 16 + quad * 4 + reg;
#pragma unroll
      for (int j = 0; j < 8; ++j) {
        const int col = qh * 128 + j * 16 + lrow;
        O[(size_t)row * 4096 + col] = f2bf(acco[i][j][reg] * inv);
      }
    }
}

// ---------- launch ----------
extern "C" void kernel_launch(void* const* d_in, const int* in_sizes, int n_in,
                              void* d_out, int out_size, void* d_ws, size_t ws_size,
                              hipStream_t stream) {
  const float* X  = (const float*)d_in[0];
  const float* Wq = (const float*)d_in[2];
  const float* Wk = (const float*)d_in[3];
  const float* Wv = (const float*)d_in[4];
  const float* Wo = (const float*)d_in[5];
  u16* ws = (u16*)d_ws;

  // workspace (u16 elements), ~120 MiB total:
  // Xb(16.7M) | R0(16.7M) | R1(16.7M) | R2(4.2M) | R3(4.2M) | R4(4.2M)
  u16* Xb = ws;
  u16* R0 = Xb + 16777216;
  u16* R1 = R0 + 16777216;
  u16* R2 = R1 + 16777216;
  u16* R3 = R2 + 4194304;
  u16* R4 = R3 + 4194304;
  u16* Qb = R1, *Kb = R3, *Vb = R4, *Vt = R2, *Ob = R0, *WoT = R1;

  convert_x<<<8192, 256, 0, stream>>>(X, Xb);

  transpose_w<<<dim3(64, 64), 256, 0, stream>>>(Wq, R0, 4096, 4096);
  gemm_bt128<0><<<dim3(32, 32), 256, 0, stream>>>(Xb, R0, Qb, 4096, 4096);

  transpose_w<<<dim3(16, 64), 256, 0, stream>>>(Wk, R0, 4096, 1024);
  gemm_bt128<0><<<dim3(8, 32), 256, 0, stream>>>(Xb, R0, Kb, 4096, 1024);

  transpose_w<<<dim3(16, 64), 256, 0, stream>>>(Wv, R0, 4096, 1024);
  gemm_bt128<0><<<dim3(8, 32), 256, 0, stream>>>(Xb, R0, Vb, 4096, 1024);

  rope_kernel<<<4096, 256, 0, stream>>>(Qb, Kb);
  transpose_v<<<dim3(2, 32, 16), 256, 0, stream>>>(Vb, Vt);

  attn<<<dim3(16, 32, 2), 256, 0, stream>>>(Qb, Kb, Vt, Ob);

  transpose_w<<<dim3(64, 64), 256, 0, stream>>>(Wo, WoT, 4096, 4096);
  gemm_bt128<1><<<dim3(32, 32), 256, 0, stream>>>(Ob, WoT, d_out, 4096, 4096);
}

// Round 3
// 1083.003 us; speedup vs baseline: 1.2353x; 1.1605x over previous
//
#include <hip/hip_runtime.h>

typedef unsigned short u16;
typedef unsigned int u32;
typedef __attribute__((ext_vector_type(8))) __bf16 bf16x8;
typedef __attribute__((ext_vector_type(4))) float f32x4;

// ---------- helpers ----------
__device__ __forceinline__ u16 f2bf(float f) {
  union { float f; u32 u; } v; v.f = f;
  u32 r = v.u + 0x7fffu + ((v.u >> 16) & 1u);   // RNE
  return (u16)(r >> 16);
}
__device__ __forceinline__ float bf2f(u16 h) {
  return __uint_as_float(((u32)h) << 16);
}
// async global->LDS, 16B per lane. LDS dest = wave-uniform base + lane*16.
__device__ __forceinline__ void gld16(void* lds, const void* g) {
  __builtin_amdgcn_global_load_lds(
      (__attribute__((address_space(1))) void*)g,
      (__attribute__((address_space(3))) void*)lds, 16, 0, 0);
}

// ---------- X conversion: fp32 -> bf16, 8 elems/thread ----------
__global__ void convert_x(const float* __restrict__ src, u16* __restrict__ dst) {
  const size_t c = (size_t)blockIdx.x * blockDim.x + threadIdx.x;  // chunk of 8
  const float* s = src + c * 8;
  u16 t[8];
#pragma unroll
  for (int i = 0; i < 8; ++i) t[i] = f2bf(s[i]);
  ((uint4*)dst)[c] = *(const uint4*)t;
}

// ---------- weight transpose: src (K x N, fp32) -> dst (N x K, bf16) ----------
__global__ void transpose_w(const float* __restrict__ srcf, u16* __restrict__ dst,
                            int K, int N) {
  __shared__ u16 tile[64][72];
  const int r0 = blockIdx.y * 64, c0 = blockIdx.x * 64;
  const int tr = threadIdx.x >> 2;          // 0..63
  const int tc = (threadIdx.x & 3) * 16;    // 0,16,32,48
  const float* src = srcf + (size_t)(r0 + tr) * N + c0 + tc;
  u16* t = &tile[tr][tc];
#pragma unroll
  for (int i = 0; i < 16; ++i) t[i] = f2bf(src[i]);
  __syncthreads();
  u16 tmp[16];
#pragma unroll
  for (int i = 0; i < 16; ++i) tmp[i] = tile[tc + i][tr];
  uint4* gd = (uint4*)(dst + (size_t)(c0 + tr) * K + r0 + tc);
  gd[0] = *(uint4*)&tmp[0];
  gd[1] = *(uint4*)&tmp[8];
}

// ---------- V transpose: V (b*2048+s, h*128+d) -> Vt[((b*8+h)*128+d)*2048 + s] ----------
__global__ void transpose_v(const u16* __restrict__ V, u16* __restrict__ Vt) {
  __shared__ u16 tile[64][72];
  const int z = blockIdx.z, b = z >> 3, h = z & 7;
  const int s0 = blockIdx.y * 64;   // s tile
  const int d0 = blockIdx.x * 64;   // d tile
  const u16* src = V + ((size_t)(b * 2048 + s0)) * 1024 + h * 128 + d0;
  u16* dst = Vt + ((size_t)((b * 8 + h) * 128 + d0)) * 2048 + s0;
  const int tr = threadIdx.x >> 2;
  const int tc = (threadIdx.x & 3) * 16;
  const uint4* gs = (const uint4*)(src + (size_t)tr * 1024 + tc);
  *(uint4*)&tile[tr][tc] = gs[0];
  *(uint4*)&tile[tr][tc + 8] = gs[1];
  __syncthreads();
  u16 tmp[16];
#pragma unroll
  for (int i = 0; i < 16; ++i) tmp[i] = tile[tc + i][tr];
  uint4* gd = (uint4*)(dst + (size_t)tr * 2048 + tc);
  gd[0] = *(uint4*)&tmp[0];
  gd[1] = *(uint4*)&tmp[8];
}

// ---------- GEMM: C[M,N] = A[M,K] * B[K,N], B given transposed (N x K) ----------
// bf16 in, fp32 acc, output bf16 (OUT32=0) or fp32 (OUT32=1).
// Tile 128x128, BK=64, 256 threads, wave -> 64x64. m97 structure.
template <int OUT32>
__global__ __launch_bounds__(256, 2) void gemm_bt128(
    const u16* __restrict__ A, const u16* __restrict__ Bt,
    void* __restrict__ Cv, int K, int N) {
  __shared__ u16 As[128 * 64];
  __shared__ u16 Bs[128 * 64];
  const int tid = threadIdx.x;
  const int wave = tid >> 6, lane = tid & 63;
  const int m0 = blockIdx.y * 128, n0 = blockIdx.x * 128;
  const int wr = (wave >> 1) * 64, wc = (wave & 1) * 64;
  const int lrow = lane & 15, quad = lane >> 4;
  const int cbase = wave * 64 + lane;     // chunk id (16B chunks), r=0

  f32x4 acc[4][4];
#pragma unroll
  for (int i = 0; i < 4; ++i)
#pragma unroll
    for (int j = 0; j < 4; ++j) acc[i][j] = (f32x4){0.f, 0.f, 0.f, 0.f};

  for (int k0 = 0; k0 < K; k0 += 64) {
#pragma unroll
    for (int r = 0; r < 4; ++r) {
      const int c = r * 256 + cbase;          // 0..1023
      const int row = c >> 3, col = (c & 7) * 8;
      gld16(&As[(size_t)(r * 4 + wave) * 512],
            A + (size_t)(m0 + row) * K + k0 + col);
      gld16(&Bs[(size_t)(r * 4 + wave) * 512],
            Bt + (size_t)(n0 + row) * K + k0 + col);
    }
    __syncthreads();   // drains vmcnt(0): tiles resident
#pragma unroll
    for (int kk = 0; kk < 2; ++kk) {
      const int ko = kk * 32 + quad * 8;
      bf16x8 af[4], bfr[4];
#pragma unroll
      for (int i = 0; i < 4; ++i)
        af[i] = *(const bf16x8*)&As[(wr + i * 16 + lrow) * 64 + ko];
#pragma unroll
      for (int j = 0; j < 4; ++j)
        bfr[j] = *(const bf16x8*)&Bs[(wc + j * 16 + lrow) * 64 + ko];
#pragma unroll
      for (int i = 0; i < 4; ++i)
#pragma unroll
        for (int j = 0; j < 4; ++j)
          acc[i][j] = __builtin_amdgcn_mfma_f32_16x16x32_bf16(af[i], bfr[j], acc[i][j], 0, 0, 0);
    }
    __syncthreads();
  }
#pragma unroll
  for (int i = 0; i < 4; ++i)
#pragma unroll
    for (int j = 0; j < 4; ++j)
#pragma unroll
      for (int reg = 0; reg < 4; ++reg) {
        const int row = m0 + wr + i * 16 + quad * 4 + reg;
        const int col = n0 + wc + j * 16 + lrow;
        if (OUT32)
          ((float*)Cv)[(size_t)row * N + col] = acc[i][j][reg];
        else
          ((u16*)Cv)[(size_t)row * N + col] = f2bf(acc[i][j][reg]);
      }
}

// ---------- RoPE in-place on Q (4096x4096) and K (4096x1024) ----------
// Q additionally pre-scaled by scale*log2(e) so attn's exp path is exp2(s-m)
// with no per-entry multiply. K unscaled.
__global__ void rope_kernel(u16* __restrict__ Q, u16* __restrict__ Kc) {
  const int row = blockIdx.x;               // b*2048 + s
  const float p = (float)(row & 2047);
  const float csc = 0.088388347762774597f * 1.4426950408889634f;
  for (int t = threadIdx.x; t < 2560; t += 256) {
    u16* base;
    int d;
    float sc;
    if (t < 2048) { const int h = t >> 6; d = t & 63; base = Q + (size_t)row * 4096 + h * 128; sc = csc; }
    else { const int tt = t - 2048; const int h = tt >> 6; d = tt & 63; base = Kc + (size_t)row * 1024 + h * 128; sc = 1.f; }
    const float inv = exp2f((float)d * -0.20762050593046807f);  // 10000^(-d/64)
    const float f = p * inv;
    float s, c;
    sincosf(f, &s, &c);
    const float x1 = bf2f(base[d]);
    const float x2 = bf2f(base[d + 64]);
    base[d] = f2bf((x1 * c - x2 * s) * sc);
    base[d + 64] = f2bf((x2 * c + x1 * s) * sc);
  }
}

// ---------- flash attention ----------
// grid (qtile=16, qhead=32, b=2), 256 threads. Wave owns 32 q-rows.
// KV-tile = 64. Static LDS 51200 B. Q frags in registers.
//
// SWAPPED QK^T (m214 structure): mfma(K,Q) puts key on the row index and q on
// the col index -> each lane holds 16 key-values for ONE q-row (q = lane&15).
// Row reduction = in-lane max/sum + 2 shfl_xor (16,32) across quads, i.e.
// 8 shuffles/iter total (was 64). P rows are lane-local -> packed 8B LDS
// writes; PV uses P as the SECOND mfma operand (contiguous row read).
// Q is pre-scaled by scale*log2e in rope, so p = exp2(s - m) directly.
// Defer-max (T13, THR=8): skip rescale pass when tile max doesn't grow.
//
// LDS XOR-swizzle on K/V/Q staging (both-sides involution, rule #21) retained.
// Pipelined staging: V(cur) issued at loop top; K(next) after mid barrier.
__global__ __launch_bounds__(256, 1) void attn(
    const u16* __restrict__ Q, const u16* __restrict__ Kc,
    const u16* __restrict__ Vt, u16* __restrict__ O) {
  __shared__ u16 smem[25600];   // 51200 bytes
  u16* Qs = smem;               // overlay: 128x128 (16384) for initial Q staging
  u16* Ks = smem;               // 64 x 128 (8192)
  u16* Vs = smem + 8192;        // 128 x 64 (8192)  row=d, col=key
  u16* Ps = smem + 16384;       // 128 x 72 (9216)  padded; row=q, col=key
  const int tid = threadIdx.x, wave = tid >> 6, lane = tid & 63;
  const int qt = blockIdx.x, qh = blockIdx.y, b = blockIdx.z;
  const int kvh = qh >> 2;
  const int lrow = lane & 15, quad = lane >> 4;
  const int swz = (lrow & 7) << 3;          // read-side XOR, element units

  // ---- stage Q tile (128 x 128) via global_load_lds (swizzled source) ----
  const u16* qb = Q + ((size_t)(b * 2048 + qt * 128)) * 4096 + qh * 128;
#pragma unroll
  for (int r = 0; r < 8; ++r) {
    const int c = (r * 4 + wave) * 64 + lane;   // 0..2047 chunks
    const int row = c >> 4, scol = (c & 15) ^ (row & 7);
    gld16(&Qs[(size_t)(r * 4 + wave) * 512],
          qb + (size_t)row * 4096 + scol * 8);
  }
  __syncthreads();
  bf16x8 aq[2][4];
#pragma unroll
  for (int i = 0; i < 2; ++i)
#pragma unroll
    for (int kk = 0; kk < 4; ++kk)
      aq[i][kk] = *(const bf16x8*)
          &Qs[(wave * 32 + i * 16 + lrow) * 128 + ((kk * 32 + quad * 8) ^ swz)];
  __syncthreads();

  // ---- prologue: stage K(0) (swizzled source), drain before first QK^T ----
  {
    const u16* kb = Kc + ((size_t)(b * 2048)) * 1024 + kvh * 128;
#pragma unroll
    for (int r = 0; r < 4; ++r) {
      const int c = (r * 4 + wave) * 64 + lane;   // 0..1023 chunks
      const int row = c >> 4, scol = (c & 15) ^ (row & 7);
      gld16(&Ks[(size_t)(r * 4 + wave) * 512],
            kb + (size_t)row * 1024 + scol * 8);
    }
  }
  __syncthreads();

  // acco[i][j][reg] = O[q = wave*32+i*16+lrow][d = j*16+quad*4+reg]
  f32x4 acco[2][8];
#pragma unroll
  for (int i = 0; i < 2; ++i)
#pragma unroll
    for (int j = 0; j < 8; ++j) acco[i][j] = (f32x4){0.f, 0.f, 0.f, 0.f};
  float m_i[2], l_i[2];
#pragma unroll
  for (int i = 0; i < 2; ++i) { m_i[i] = -INFINITY; l_i[i] = 0.f; }

  const u16* vbase = Vt + ((size_t)((b * 8 + kvh) * 128)) * 2048;

  for (int kv0 = 0; kv0 < 2048; kv0 += 64) {
    // ---- issue V(kv0): 128 d x 64 keys (swizzled source); hides under QK^T ----
#pragma unroll
    for (int r = 0; r < 4; ++r) {
      const int c = (r * 4 + wave) * 64 + lane;   // 0..1023 chunks
      const int row = c >> 3, scol = (c & 7) ^ (row & 7);
      gld16(&Vs[(size_t)(r * 4 + wave) * 512],
            vbase + (size_t)row * 2048 + kv0 + scol * 8);
    }

    // ---- S^T = K Q^T: s[i][j][reg] = S[key = j*16+quad*4+reg][q = lrow] ----
    f32x4 s[2][4];
#pragma unroll
    for (int i = 0; i < 2; ++i)
#pragma unroll
      for (int j = 0; j < 4; ++j) s[i][j] = (f32x4){0.f, 0.f, 0.f, 0.f};
    __builtin_amdgcn_s_setprio(1);
#pragma unroll
    for (int kk = 0; kk < 4; ++kk) {
      const int ko = (kk * 32 + quad * 8) ^ swz;
#pragma unroll
      for (int j = 0; j < 4; ++j) {
        const bf16x8 bk = *(const bf16x8*)&Ks[(j * 16 + lrow) * 128 + ko];
        s[0][j] = __builtin_amdgcn_mfma_f32_16x16x32_bf16(bk, aq[0][kk], s[0][j], 0, 0, 0);
        s[1][j] = __builtin_amdgcn_mfma_f32_16x16x32_bf16(bk, aq[1][kk], s[1][j], 0, 0, 0);
      }
    }
    __builtin_amdgcn_s_setprio(0);

    // ---- online softmax: per q-group, in-lane reduce + 2 shuffles ----
#pragma unroll
    for (int i = 0; i < 2; ++i) {
      float mx = s[i][0][0];
#pragma unroll
      for (int j = 0; j < 4; ++j)
#pragma unroll
        for (int reg = 0; reg < 4; ++reg) mx = fmaxf(mx, s[i][j][reg]);
      mx = fmaxf(mx, __shfl_xor(mx, 16));
      mx = fmaxf(mx, __shfl_xor(mx, 32));
      const bool grow = !__all(mx <= m_i[i] + 8.f);   // defer-max THR=8
      float mnew = m_i[i], al = 1.f;
      if (grow) {
        mnew = fmaxf(m_i[i], mx);
        al = exp2f(m_i[i] - mnew);
        m_i[i] = mnew;
      }
      float rs = 0.f;
#pragma unroll
      for (int j = 0; j < 4; ++j)
#pragma unroll
        for (int reg = 0; reg < 4; ++reg) {
          const float p0 = exp2f(s[i][j][reg] - mnew);
          s[i][j][reg] = p0;
          rs += p0;
        }
      rs += __shfl_xor(rs, 16);
      rs += __shfl_xor(rs, 32);
      l_i[i] = l_i[i] * al + rs;
      if (grow) {
#pragma unroll
        for (int j = 0; j < 8; ++j)
#pragma unroll
          for (int reg = 0; reg < 4; ++reg) acco[i][j][reg] *= al;
      }
    }

    // ---- P -> LDS: packed 8B writes (4 consecutive keys per lane) ----
#pragma unroll
    for (int i = 0; i < 2; ++i)
#pragma unroll
      for (int j = 0; j < 4; ++j) {
        u16 t4[4];
#pragma unroll
        for (int reg = 0; reg < 4; ++reg) t4[reg] = f2bf(s[i][j][reg]);
        *(uint2*)&Ps[(wave * 32 + i * 16 + lrow) * 72 + j * 16 + quad * 4] =
            *(const uint2*)t4;
      }
    __syncthreads();   // drains V loads + P writes; all waves past QK^T (Ks free)

    // ---- issue K(kv0+64) (swizzled source): hides under PV ----
    if (kv0 + 64 < 2048) {
      const u16* kb = Kc + ((size_t)(b * 2048 + kv0 + 64)) * 1024 + kvh * 128;
#pragma unroll
      for (int r = 0; r < 4; ++r) {
        const int c = (r * 4 + wave) * 64 + lane;
        const int row = c >> 4, scol = (c & 15) ^ (row & 7);
        gld16(&Ks[(size_t)(r * 4 + wave) * 512],
              kb + (size_t)row * 1024 + scol * 8);
      }
    }

    // ---- O^T += V P^T: first operand = V-frag (d rows), second = P-frag ----
    __builtin_amdgcn_s_setprio(1);
#pragma unroll
    for (int kk = 0; kk < 2; ++kk) {
      const int ko = kk * 32 + quad * 8;
      const int kov = ko ^ swz;
      const bf16x8 ap0 = *(const bf16x8*)&Ps[(wave * 32 + lrow) * 72 + ko];
      const bf16x8 ap1 = *(const bf16x8*)&Ps[(wave * 32 + 16 + lrow) * 72 + ko];
#pragma unroll
      for (int j = 0; j < 8; ++j) {
        const bf16x8 bv = *(const bf16x8*)&Vs[(j * 16 + lrow) * 64 + kov];
        acco[0][j] = __builtin_amdgcn_mfma_f32_16x16x32_bf16(bv, ap0, acco[0][j], 0, 0, 0);
        acco[1][j] = __builtin_amdgcn_mfma_f32_16x16x32_bf16(bv, ap1, acco[1][j], 0, 0, 0);
      }
    }
    __builtin_amdgcn_s_setprio(0);
    __syncthreads();   // drains K(next) prefetch; PV reads of Vs/Ps complete
  }

  // ---- epilogue: O[q][qh*128+d], 4 consecutive d per lane -> 8B stores ----
#pragma unroll
  for (int i = 0; i < 2; ++i) {
    const float inv = 1.0f / l_i[i];
    const int row = b * 2048 + qt * 128 + wave * 32 + i * 16 + lrow;
#pragma unroll
    for (int j = 0; j < 8; ++j) {
      u16 t4[4];
#pragma unroll
      for (int reg = 0; reg < 4; ++reg) t4[reg] = f2bf(acco[i][j][reg] * inv);
      *(uint2*)&O[(size_t)row * 4096 + qh * 128 + j * 16 + quad * 4] =
          *(const uint2*)t4;
    }
  }
}

// ---------- launch ----------
extern "C" void kernel_launch(void* const* d_in, const int* in_sizes, int n_in,
                              void* d_out, int out_size, void* d_ws, size_t ws_size,
                              hipStream_t stream) {
  const float* X  = (const float*)d_in[0];
  const float* Wq = (const float*)d_in[2];
  const float* Wk = (const float*)d_in[3];
  const float* Wv = (const float*)d_in[4];
  const float* Wo = (const float*)d_in[5];
  u16* ws = (u16*)d_ws;

  u16* Xb = ws;
  u16* R0 = Xb + 16777216;
  u16* R1 = R0 + 16777216;
  u16* R2 = R1 + 16777216;
  u16* R3 = R2 + 4194304;
  u16* R4 = R3 + 4194304;
  u16* Qb = R1, *Kb = R3, *Vb = R4, *Vt = R2, *Ob = R0, *WoT = R1;

  convert_x<<<8192, 256, 0, stream>>>(X, Xb);

  transpose_w<<<dim3(64, 64), 256, 0, stream>>>(Wq, R0, 4096, 4096);
  gemm_bt128<0><<<dim3(32, 32), 256, 0, stream>>>(Xb, R0, Qb, 4096, 4096);

  transpose_w<<<dim3(16, 64), 256, 0, stream>>>(Wk, R0, 4096, 1024);
  gemm_bt128<0><<<dim3(8, 32), 256, 0, stream>>>(Xb, R0, Kb, 4096, 1024);

  transpose_w<<<dim3(16, 64), 256, 0, stream>>>(Wv, R0, 4096, 1024);
  gemm_bt128<0><<<dim3(8, 32), 256, 0, stream>>>(Xb, R0, Vb, 4096, 1024);

  rope_kernel<<<4096, 256, 0, stream>>>(Qb, Kb);
  transpose_v<<<dim3(2, 32, 16), 256, 0, stream>>>(Vb, Vt);

  attn<<<dim3(16, 32, 2), 256, 0, stream>>>(Qb, Kb, Vt, Ob);

  transpose_w<<<dim3(64, 64), 256, 0, stream>>>(Wo, WoT, 4096, 4096);
  gemm_bt128<1><<<dim3(32, 32), 256, 0, stream>>>(Ob, WoT, d_out, 4096, 4096);
}

// Round 4
// 1064.791 us; speedup vs baseline: 1.2564x; 1.0171x over previous
//
#include <hip/hip_runtime.h>

typedef unsigned short u16;
typedef unsigned int u32;
typedef __attribute__((ext_vector_type(8))) __bf16 bf16x8;
typedef __attribute__((ext_vector_type(4))) float f32x4;
typedef __attribute__((ext_vector_type(4))) u32 u32x4;

// ---------- helpers ----------
__device__ __forceinline__ u16 f2bf(float f) {
  union { float f; u32 u; } v; v.f = f;
  u32 r = v.u + 0x7fffu + ((v.u >> 16) & 1u);   // RNE
  return (u16)(r >> 16);
}
__device__ __forceinline__ float bf2f(u16 h) {
  return __uint_as_float(((u32)h) << 16);
}
__device__ __forceinline__ u32 pk2(float a, float b) {
  return (u32)f2bf(a) | ((u32)f2bf(b) << 16);
}
// async global->LDS, 16B per lane. LDS dest = wave-uniform base + lane*16.
__device__ __forceinline__ void gld16(void* lds, const void* g) {
  __builtin_amdgcn_global_load_lds(
      (__attribute__((address_space(1))) void*)g,
      (__attribute__((address_space(3))) void*)lds, 16, 0, 0);
}

// ---------- X conversion: fp32 -> bf16, 8 elems/thread ----------
__global__ void convert_x(const float* __restrict__ src, u16* __restrict__ dst) {
  const size_t c = (size_t)blockIdx.x * blockDim.x + threadIdx.x;  // chunk of 8
  const float* s = src + c * 8;
  u16 t[8];
#pragma unroll
  for (int i = 0; i < 8; ++i) t[i] = f2bf(s[i]);
  ((uint4*)dst)[c] = *(const uint4*)t;
}

// ---------- weight transpose: src (K x N, fp32) -> dst (N x K, bf16) ----------
__global__ void transpose_w(const float* __restrict__ srcf, u16* __restrict__ dst,
                            int K, int N) {
  __shared__ u16 tile[64][72];
  const int r0 = blockIdx.y * 64, c0 = blockIdx.x * 64;
  const int tr = threadIdx.x >> 2;          // 0..63
  const int tc = (threadIdx.x & 3) * 16;    // 0,16,32,48
  const float* src = srcf + (size_t)(r0 + tr) * N + c0 + tc;
  u16* t = &tile[tr][tc];
#pragma unroll
  for (int i = 0; i < 16; ++i) t[i] = f2bf(src[i]);
  __syncthreads();
  u16 tmp[16];
#pragma unroll
  for (int i = 0; i < 16; ++i) tmp[i] = tile[tc + i][tr];
  uint4* gd = (uint4*)(dst + (size_t)(c0 + tr) * K + r0 + tc);
  gd[0] = *(uint4*)&tmp[0];
  gd[1] = *(uint4*)&tmp[8];
}

// ---------- V transpose: V (b*2048+s, h*128+d) -> Vt[((b*8+h)*128+d)*2048 + s] ----------
__global__ void transpose_v(const u16* __restrict__ V, u16* __restrict__ Vt) {
  __shared__ u16 tile[64][72];
  const int z = blockIdx.z, b = z >> 3, h = z & 7;
  const int s0 = blockIdx.y * 64;   // s tile
  const int d0 = blockIdx.x * 64;   // d tile
  const u16* src = V + ((size_t)(b * 2048 + s0)) * 1024 + h * 128 + d0;
  u16* dst = Vt + ((size_t)((b * 8 + h) * 128 + d0)) * 2048 + s0;
  const int tr = threadIdx.x >> 2;
  const int tc = (threadIdx.x & 3) * 16;
  const uint4* gs = (const uint4*)(src + (size_t)tr * 1024 + tc);
  *(uint4*)&tile[tr][tc] = gs[0];
  *(uint4*)&tile[tr][tc + 8] = gs[1];
  __syncthreads();
  u16 tmp[16];
#pragma unroll
  for (int i = 0; i < 16; ++i) tmp[i] = tile[tc + i][tr];
  uint4* gd = (uint4*)(dst + (size_t)tr * 2048 + tc);
  gd[0] = *(uint4*)&tmp[0];
  gd[1] = *(uint4*)&tmp[8];
}

// ---------- GEMM: C[M,N] = A[M,K] * B[K,N], B given transposed (N x K) ----------
// bf16 in, fp32 acc, output bf16 (OUT32=0) or fp32 (OUT32=1).
// Tile 128x128, BK=64, 256 threads, wave -> 64x64. m97 structure.
template <int OUT32>
__global__ __launch_bounds__(256, 2) void gemm_bt128(
    const u16* __restrict__ A, const u16* __restrict__ Bt,
    void* __restrict__ Cv, int K, int N) {
  __shared__ u16 As[128 * 64];
  __shared__ u16 Bs[128 * 64];
  const int tid = threadIdx.x;
  const int wave = tid >> 6, lane = tid & 63;
  const int m0 = blockIdx.y * 128, n0 = blockIdx.x * 128;
  const int wr = (wave >> 1) * 64, wc = (wave & 1) * 64;
  const int lrow = lane & 15, quad = lane >> 4;
  const int cbase = wave * 64 + lane;     // chunk id (16B chunks), r=0

  f32x4 acc[4][4];
#pragma unroll
  for (int i = 0; i < 4; ++i)
#pragma unroll
    for (int j = 0; j < 4; ++j) acc[i][j] = (f32x4){0.f, 0.f, 0.f, 0.f};

  for (int k0 = 0; k0 < K; k0 += 64) {
#pragma unroll
    for (int r = 0; r < 4; ++r) {
      const int c = r * 256 + cbase;          // 0..1023
      const int row = c >> 3, col = (c & 7) * 8;
      gld16(&As[(size_t)(r * 4 + wave) * 512],
            A + (size_t)(m0 + row) * K + k0 + col);
      gld16(&Bs[(size_t)(r * 4 + wave) * 512],
            Bt + (size_t)(n0 + row) * K + k0 + col);
    }
    __syncthreads();   // drains vmcnt(0): tiles resident
#pragma unroll
    for (int kk = 0; kk < 2; ++kk) {
      const int ko = kk * 32 + quad * 8;
      bf16x8 af[4], bfr[4];
#pragma unroll
      for (int i = 0; i < 4; ++i)
        af[i] = *(const bf16x8*)&As[(wr + i * 16 + lrow) * 64 + ko];
#pragma unroll
      for (int j = 0; j < 4; ++j)
        bfr[j] = *(const bf16x8*)&Bs[(wc + j * 16 + lrow) * 64 + ko];
#pragma unroll
      for (int i = 0; i < 4; ++i)
#pragma unroll
        for (int j = 0; j < 4; ++j)
          acc[i][j] = __builtin_amdgcn_mfma_f32_16x16x32_bf16(af[i], bfr[j], acc[i][j], 0, 0, 0);
    }
    __syncthreads();
  }
#pragma unroll
  for (int i = 0; i < 4; ++i)
#pragma unroll
    for (int j = 0; j < 4; ++j)
#pragma unroll
      for (int reg = 0; reg < 4; ++reg) {
        const int row = m0 + wr + i * 16 + quad * 4 + reg;
        const int col = n0 + wc + j * 16 + lrow;
        if (OUT32)
          ((float*)Cv)[(size_t)row * N + col] = acc[i][j][reg];
        else
          ((u16*)Cv)[(size_t)row * N + col] = f2bf(acc[i][j][reg]);
      }
}

// ---------- RoPE in-place on Q (4096x4096) and K (4096x1024) ----------
// Q additionally pre-scaled by scale*log2(e) so attn's exp path is exp2(s-m).
__global__ void rope_kernel(u16* __restrict__ Q, u16* __restrict__ Kc) {
  const int row = blockIdx.x;               // b*2048 + s
  const float p = (float)(row & 2047);
  const float csc = 0.088388347762774597f * 1.4426950408889634f;
  for (int t = threadIdx.x; t < 2560; t += 256) {
    u16* base;
    int d;
    float sc;
    if (t < 2048) { const int h = t >> 6; d = t & 63; base = Q + (size_t)row * 4096 + h * 128; sc = csc; }
    else { const int tt = t - 2048; const int h = tt >> 6; d = tt & 63; base = Kc + (size_t)row * 1024 + h * 128; sc = 1.f; }
    const float inv = exp2f((float)d * -0.20762050593046807f);  // 10000^(-d/64)
    const float f = p * inv;
    float s, c;
    sincosf(f, &s, &c);
    const float x1 = bf2f(base[d]);
    const float x2 = bf2f(base[d + 64]);
    base[d] = f2bf((x1 * c - x2 * s) * sc);
    base[d + 64] = f2bf((x2 * c + x1 * s) * sc);
  }
}

// ---------- flash attention ----------
// grid (qtile=16, qhead=32, b=2), 256 threads. Wave owns 32 q-rows.
// KV-tile = 64. Static LDS 32768 B (Ks+Vs only; no P buffer).
//
// SWAPPED QK^T: mfma(K,Q) -> lane holds 16 key-values per q-row (q = lane&15).
// KEY-PERMUTED K STAGING (this round): LDS row m holds physical K row
// srcrow(m) = 32*(m>>5) + 8*((m>>2)&3) + 4*((m>>4)&1) + (m&3)  (bit shuffle).
// With that permutation, the P values a lane produces in QK^T are EXACTLY its
// PV B-fragment: ap_kk = [s[2kk].regs, s[2kk+1].regs] -- pure register pack,
// no LDS round-trip, no shuffles. V staging stays identity (PV key order =
// physical). Softmax/PV sums are key-permutation-invariant.
// Defer-max (T13, THR=8). XOR-swizzle on all staged tiles (rule #21 pattern).
// Pipelined staging: V(cur) issued at loop top; K(next) after mid barrier.
__global__ __launch_bounds__(256, 3) void attn(
    const u16* __restrict__ Q, const u16* __restrict__ Kc,
    const u16* __restrict__ Vt, u16* __restrict__ O) {
  __shared__ u16 smem[16384];   // 32768 bytes
  u16* Qs = smem;               // overlay: 128x128 (16384) for initial Q staging
  u16* Ks = smem;               // 64 x 128 (8192 u16)   row=permuted key, col=d
  u16* Vs = smem + 8192;        // 128 x 64 (8192 u16)   row=d, col=key
  const int tid = threadIdx.x, wave = tid >> 6, lane = tid & 63;
  const int qt = blockIdx.x, qh = blockIdx.y, b = blockIdx.z;
  const int kvh = qh >> 2;
  const int lrow = lane & 15, quad = lane >> 4;
  const int swz = (lrow & 7) << 3;          // read-side XOR, element units

  // ---- stage Q tile (128 x 128) via global_load_lds (swizzled source) ----
  const u16* qb = Q + ((size_t)(b * 2048 + qt * 128)) * 4096 + qh * 128;
#pragma unroll
  for (int r = 0; r < 8; ++r) {
    const int c = (r * 4 + wave) * 64 + lane;   // 0..2047 chunks
    const int row = c >> 4, scol = (c & 15) ^ (row & 7);
    gld16(&Qs[(size_t)(r * 4 + wave) * 512],
          qb + (size_t)row * 4096 + scol * 8);
  }
  __syncthreads();
  bf16x8 aq[2][4];
#pragma unroll
  for (int i = 0; i < 2; ++i)
#pragma unroll
    for (int kk = 0; kk < 4; ++kk)
      aq[i][kk] = *(const bf16x8*)
          &Qs[(wave * 32 + i * 16 + lrow) * 128 + ((kk * 32 + quad * 8) ^ swz)];
  __syncthreads();

  // ---- prologue: stage K(0) (permuted rows, swizzled source) ----
  {
    const u16* kb = Kc + ((size_t)(b * 2048)) * 1024 + kvh * 128;
#pragma unroll
    for (int r = 0; r < 4; ++r) {
      const int c = (r * 4 + wave) * 64 + lane;   // 0..1023 chunks
      const int m = c >> 4, scol = (c & 15) ^ (m & 7);
      const int srcrow = ((m >> 5) << 5) | (((m >> 2) & 3) << 3) |
                         (((m >> 4) & 1) << 2) | (m & 3);
      gld16(&Ks[(size_t)(r * 4 + wave) * 512],
            kb + (size_t)srcrow * 1024 + scol * 8);
    }
  }
  __syncthreads();

  // acco[i][j][reg] = O[q = wave*32+i*16+lrow][d = j*16+quad*4+reg]
  f32x4 acco[2][8];
#pragma unroll
  for (int i = 0; i < 2; ++i)
#pragma unroll
    for (int j = 0; j < 8; ++j) acco[i][j] = (f32x4){0.f, 0.f, 0.f, 0.f};
  float m_i[2], l_i[2];
#pragma unroll
  for (int i = 0; i < 2; ++i) { m_i[i] = -INFINITY; l_i[i] = 0.f; }

  const u16* vbase = Vt + ((size_t)((b * 8 + kvh) * 128)) * 2048;

  for (int kv0 = 0; kv0 < 2048; kv0 += 64) {
    // ---- issue V(kv0): 128 d x 64 keys (identity key order); hides under QK^T ----
#pragma unroll
    for (int r = 0; r < 4; ++r) {
      const int c = (r * 4 + wave) * 64 + lane;   // 0..1023 chunks
      const int row = c >> 3, scol = (c & 7) ^ (row & 7);
      gld16(&Vs[(size_t)(r * 4 + wave) * 512],
            vbase + (size_t)row * 2048 + kv0 + scol * 8);
    }

    // ---- S^T = K Q^T: s[i][j][reg] = S[LDS key-row j*16+quad*4+reg][q=lrow] ----
    f32x4 s[2][4];
#pragma unroll
    for (int i = 0; i < 2; ++i)
#pragma unroll
      for (int j = 0; j < 4; ++j) s[i][j] = (f32x4){0.f, 0.f, 0.f, 0.f};
    __builtin_amdgcn_s_setprio(1);
#pragma unroll
    for (int kk = 0; kk < 4; ++kk) {
      const int ko = (kk * 32 + quad * 8) ^ swz;
#pragma unroll
      for (int j = 0; j < 4; ++j) {
        const bf16x8 bk = *(const bf16x8*)&Ks[(j * 16 + lrow) * 128 + ko];
        s[0][j] = __builtin_amdgcn_mfma_f32_16x16x32_bf16(bk, aq[0][kk], s[0][j], 0, 0, 0);
        s[1][j] = __builtin_amdgcn_mfma_f32_16x16x32_bf16(bk, aq[1][kk], s[1][j], 0, 0, 0);
      }
    }
    __builtin_amdgcn_s_setprio(0);

    // ---- online softmax: per q-group, in-lane reduce + 2 shuffles ----
#pragma unroll
    for (int i = 0; i < 2; ++i) {
      float mx = s[i][0][0];
#pragma unroll
      for (int j = 0; j < 4; ++j)
#pragma unroll
        for (int reg = 0; reg < 4; ++reg) mx = fmaxf(mx, s[i][j][reg]);
      mx = fmaxf(mx, __shfl_xor(mx, 16));
      mx = fmaxf(mx, __shfl_xor(mx, 32));
      const bool grow = !__all(mx <= m_i[i] + 8.f);   // defer-max THR=8
      float mnew = m_i[i], al = 1.f;
      if (grow) {
        mnew = fmaxf(m_i[i], mx);
        al = exp2f(m_i[i] - mnew);
        m_i[i] = mnew;
      }
      float rs = 0.f;
#pragma unroll
      for (int j = 0; j < 4; ++j)
#pragma unroll
        for (int reg = 0; reg < 4; ++reg) {
          const float p0 = exp2f(s[i][j][reg] - mnew);
          s[i][j][reg] = p0;
          rs += p0;
        }
      rs += __shfl_xor(rs, 16);
      rs += __shfl_xor(rs, 32);
      l_i[i] = l_i[i] * al + rs;
      if (grow) {
#pragma unroll
        for (int j = 0; j < 8; ++j)
#pragma unroll
          for (int reg = 0; reg < 4; ++reg) acco[i][j][reg] *= al;
      }
    }

    // ---- pack P into PV B-fragments (register only; key-permute makes this exact) ----
    u32x4 pw[2][2];
#pragma unroll
    for (int i = 0; i < 2; ++i)
#pragma unroll
      for (int kk = 0; kk < 2; ++kk) {
        pw[i][kk].x = pk2(s[i][2 * kk][0], s[i][2 * kk][1]);
        pw[i][kk].y = pk2(s[i][2 * kk][2], s[i][2 * kk][3]);
        pw[i][kk].z = pk2(s[i][2 * kk + 1][0], s[i][2 * kk + 1][1]);
        pw[i][kk].w = pk2(s[i][2 * kk + 1][2], s[i][2 * kk + 1][3]);
      }
    __syncthreads();   // drains V loads; all waves past QK^T (Ks free)

    // ---- issue K(kv0+64) (permuted rows, swizzled source): hides under PV ----
    if (kv0 + 64 < 2048) {
      const u16* kb = Kc + ((size_t)(b * 2048 + kv0 + 64)) * 1024 + kvh * 128;
#pragma unroll
      for (int r = 0; r < 4; ++r) {
        const int c = (r * 4 + wave) * 64 + lane;
        const int m = c >> 4, scol = (c & 15) ^ (m & 7);
        const int srcrow = ((m >> 5) << 5) | (((m >> 2) & 3) << 3) |
                           (((m >> 4) & 1) << 2) | (m & 3);
        gld16(&Ks[(size_t)(r * 4 + wave) * 512],
              kb + (size_t)srcrow * 1024 + scol * 8);
      }
    }

    // ---- O^T += V P^T: A = V-frag from LDS, B = P-frag from registers ----
    __builtin_amdgcn_s_setprio(1);
#pragma unroll
    for (int kk = 0; kk < 2; ++kk) {
      const int kov = (kk * 32 + quad * 8) ^ swz;
      const bf16x8 ap0 = __builtin_bit_cast(bf16x8, pw[0][kk]);
      const bf16x8 ap1 = __builtin_bit_cast(bf16x8, pw[1][kk]);
#pragma unroll
      for (int j = 0; j < 8; ++j) {
        const bf16x8 bv = *(const bf16x8*)&Vs[(j * 16 + lrow) * 64 + kov];
        acco[0][j] = __builtin_amdgcn_mfma_f32_16x16x32_bf16(bv, ap0, acco[0][j], 0, 0, 0);
        acco[1][j] = __builtin_amdgcn_mfma_f32_16x16x32_bf16(bv, ap1, acco[1][j], 0, 0, 0);
      }
    }
    __builtin_amdgcn_s_setprio(0);
    __syncthreads();   // drains K(next) prefetch; PV reads of Vs complete
  }

  // ---- epilogue: O[q][qh*128+d], 4 consecutive d per lane -> 8B stores ----
#pragma unroll
  for (int i = 0; i < 2; ++i) {
    const float inv = 1.0f / l_i[i];
    const int row = b * 2048 + qt * 128 + wave * 32 + i * 16 + lrow;
#pragma unroll
    for (int j = 0; j < 8; ++j) {
      u16 t4[4];
#pragma unroll
      for (int reg = 0; reg < 4; ++reg) t4[reg] = f2bf(acco[i][j][reg] * inv);
      *(uint2*)&O[(size_t)row * 4096 + qh * 128 + j * 16 + quad * 4] =
          *(const uint2*)t4;
    }
  }
}

// ---------- launch ----------
extern "C" void kernel_launch(void* const* d_in, const int* in_sizes, int n_in,
                              void* d_out, int out_size, void* d_ws, size_t ws_size,
                              hipStream_t stream) {
  const float* X  = (const float*)d_in[0];
  const float* Wq = (const float*)d_in[2];
  const float* Wk = (const float*)d_in[3];
  const float* Wv = (const float*)d_in[4];
  const float* Wo = (const float*)d_in[5];
  u16* ws = (u16*)d_ws;

  u16* Xb = ws;
  u16* R0 = Xb + 16777216;
  u16* R1 = R0 + 16777216;
  u16* R2 = R1 + 16777216;
  u16* R3 = R2 + 4194304;
  u16* R4 = R3 + 4194304;
  u16* Qb = R1, *Kb = R3, *Vb = R4, *Vt = R2, *Ob = R0, *WoT = R1;

  convert_x<<<8192, 256, 0, stream>>>(X, Xb);

  transpose_w<<<dim3(64, 64), 256, 0, stream>>>(Wq, R0, 4096, 4096);
  gemm_bt128<0><<<dim3(32, 32), 256, 0, stream>>>(Xb, R0, Qb, 4096, 4096);

  transpose_w<<<dim3(16, 64), 256, 0, stream>>>(Wk, R0, 4096, 1024);
  gemm_bt128<0><<<dim3(8, 32), 256, 0, stream>>>(Xb, R0, Kb, 4096, 1024);

  transpose_w<<<dim3(16, 64), 256, 0, stream>>>(Wv, R0, 4096, 1024);
  gemm_bt128<0><<<dim3(8, 32), 256, 0, stream>>>(Xb, R0, Vb, 4096, 1024);

  rope_kernel<<<4096, 256, 0, stream>>>(Qb, Kb);
  transpose_v<<<dim3(2, 32, 16), 256, 0, stream>>>(Vb, Vt);

  attn<<<dim3(16, 32, 2), 256, 0, stream>>>(Qb, Kb, Vt, Ob);

  transpose_w<<<dim3(64, 64), 256, 0, stream>>>(Wo, WoT, 4096, 4096);
  gemm_bt128<1><<<dim3(32, 32), 256, 0, stream>>>(Ob, WoT, d_out, 4096, 4096);
}